// Round 2
// baseline (48552.139 us; speedup 1.0000x reference)
//
#include <hip/hip_runtime.h>
#include <math.h>
#include <stdint.h>

#define Bn 256
#define Tn 256
#define Dn 512
#define UNITSn 1024
#define NCn 512
#define G4n 4096
#define KTn 1536   // 512 (x) + 1024 (h)

typedef unsigned long long u64;

__device__ __forceinline__ double hsigd(double z) {
    return fmin(fmax(0.2 * z + 0.5, 0.0), 1.0);
}

// pack logit+col into u64: fixed-point (logit+2048)*2^40 (<<10) | (1023-col)
// monotone in logit (9.1e-13 resolution), ties -> smallest col (numpy first-max)
__device__ __forceinline__ u64 packlc(double v, int col) {
    double s = (v + 2048.0) * 1099511627776.0;   // 2^40
    u64 q = (u64)s;                              // < 2^53
    return (q << 10) | (u64)(1023 - col);
}

// ---------------- Kernel A: z = x_t@Wx + h@U (+ W[512+idx] + b) -> gates -> c,h ----
// block: 64 batch rows x 16 units (x4 gates = 64 cols), K=1536, 256 threads, fp64 math
#define A_BM 64
#define A_UN 16
#define A_BC 64
#define A_KC 32

__global__ __launch_bounds__(256) void lstm_step(
    const float* __restrict__ x, const float* __restrict__ W,
    const float* __restrict__ U, const float* __restrict__ bias,
    const double* __restrict__ hin, double* __restrict__ hout,
    double* __restrict__ cst,
    const u64* __restrict__ slots_prev, u64* __restrict__ slots_cur,
    int* __restrict__ out, int t)
{
    __shared__ double As[A_KC][68];         // 17408 B, [k][row], 32B-aligned rows
    __shared__ float  Bs[A_KC][A_BC];       // 8192 B
    __shared__ double zex[A_BM][A_BC + 1];  // 33280 B gate exchange (fp64!)
    __shared__ int    idx_lds[A_BM];

    const int tid = threadIdx.x;
    const int u0 = blockIdx.x * A_UN;       // 0..1008
    const int rowbase = blockIdx.y * A_BM;  // 0..192

    // decode prev argmax, emit out[:, t-1], zero the slot buffer C(t) will use
    if (tid < A_BM) {
        int idx = 0;
        if (t > 0) {
            u64 s = slots_prev[rowbase + tid];
            idx = 1023 - (int)(s & 1023ull);
            if (blockIdx.x == 0) out[(size_t)(rowbase + tid) * Tn + (t - 1)] = idx;
        }
        idx_lds[tid] = idx;
        if (blockIdx.x == 0) slots_cur[rowbase + tid] = 0ull;
    }

    double acc[4][4];
    #pragma unroll
    for (int i = 0; i < 4; i++)
        #pragma unroll
        for (int j = 0; j < 4; j++) acc[i][j] = 0.0;

    const int r0 = (tid >> 4) * 4;          // 0..60 (broadcast across 16 lanes)
    const int c0 = (tid & 15) * 4;          // 0..60

    // A loader: row = tid>>2, k0 = (tid&3)*4; covers k0..k0+3 and k0+16..k0+19
    const int la_row = tid >> 2;
    const int la_k0 = (tid & 3) * 4;
    // B loader: gate = tid&3, j0 = ((tid>>2)&3)*4, kk = tid>>4 (+16)
    const int lb_g  = tid & 3;
    const int lb_j0 = ((tid >> 2) & 3) * 4;
    const int lb_kk = tid >> 4;

    const size_t xrow = (size_t)(rowbase + la_row) * (Tn * (size_t)Dn) + (size_t)t * Dn;
    const size_t hrow = (size_t)(rowbase + la_row) * UNITSn;

    for (int kb = 0; kb < KTn; kb += A_KC) {
        // ---- stage A tile (transposed, fp64) ----
        {
            int k0 = kb + la_k0;
            if (k0 < Dn) {
                float4 v0 = *(const float4*)(x + xrow + k0);
                float4 v1 = *(const float4*)(x + xrow + k0 + 16);
                As[la_k0 + 0][la_row] = (double)v0.x;
                As[la_k0 + 1][la_row] = (double)v0.y;
                As[la_k0 + 2][la_row] = (double)v0.z;
                As[la_k0 + 3][la_row] = (double)v0.w;
                As[la_k0 + 16][la_row] = (double)v1.x;
                As[la_k0 + 17][la_row] = (double)v1.y;
                As[la_k0 + 18][la_row] = (double)v1.z;
                As[la_k0 + 19][la_row] = (double)v1.w;
            } else {
                const double* hp = hin + hrow + (k0 - Dn);
                double2 h0v = *(const double2*)(hp + 0);
                double2 h1v = *(const double2*)(hp + 2);
                double2 h2v = *(const double2*)(hp + 16);
                double2 h3v = *(const double2*)(hp + 18);
                As[la_k0 + 0][la_row] = h0v.x;
                As[la_k0 + 1][la_row] = h0v.y;
                As[la_k0 + 2][la_row] = h1v.x;
                As[la_k0 + 3][la_row] = h1v.y;
                As[la_k0 + 16][la_row] = h2v.x;
                As[la_k0 + 17][la_row] = h2v.y;
                As[la_k0 + 18][la_row] = h3v.x;
                As[la_k0 + 19][la_row] = h3v.y;
            }
        }
        // ---- stage B tile (fp32, exact when converted) ----
        #pragma unroll
        for (int it = 0; it < 2; it++) {
            int kk = lb_kk + it * 16;
            int k = kb + kk;
            const float* rowp = (k < Dn) ? (W + (size_t)k * G4n)
                                         : (U + (size_t)(k - Dn) * G4n);
            float4 v = *(const float4*)(rowp + lb_g * UNITSn + u0 + lb_j0);
            *(float4*)&Bs[kk][lb_g * A_UN + lb_j0] = v;
        }
        __syncthreads();
        #pragma unroll
        for (int kk = 0; kk < A_KC; kk++) {
            double2 a01 = *(const double2*)&As[kk][r0];
            double2 a23 = *(const double2*)&As[kk][r0 + 2];
            float4 b4 = *(const float4*)&Bs[kk][c0];
            double ad[4] = {a01.x, a01.y, a23.x, a23.y};
            double bd[4] = {(double)b4.x, (double)b4.y, (double)b4.z, (double)b4.w};
            #pragma unroll
            for (int i = 0; i < 4; i++)
                #pragma unroll
                for (int j = 0; j < 4; j++)
                    acc[i][j] = fma(ad[i], bd[j], acc[i][j]);
        }
        __syncthreads();
    }

    // ---- gate exchange through LDS (fp64) ----
    #pragma unroll
    for (int i = 0; i < 4; i++)
        #pragma unroll
        for (int j = 0; j < 4; j++)
            zex[r0 + i][c0 + j] = acc[i][j];
    __syncthreads();

    const int eu = tid & 15;
    const int er0 = tid >> 4;
    const int ug = u0 + eu;
    const double bi0 = (double)bias[ug];
    const double bf0 = (double)bias[UNITSn + ug];
    const double bc0 = (double)bias[2 * UNITSn + ug];
    const double bo0 = (double)bias[3 * UNITSn + ug];

    #pragma unroll
    for (int q = 0; q < 4; q++) {
        int r = er0 + q * 16;
        int rowg = rowbase + r;
        double zi = zex[r][eu]            + bi0;
        double zf = zex[r][A_UN + eu]     + bf0;
        double zc = zex[r][2 * A_UN + eu] + bc0;
        double zo = zex[r][3 * A_UN + eu] + bo0;
        if (t > 0) {
            const float* wrow = W + (size_t)(Dn + idx_lds[r]) * G4n;
            zi += (double)wrow[ug];
            zf += (double)wrow[UNITSn + ug];
            zc += (double)wrow[2 * UNITSn + ug];
            zo += (double)wrow[3 * UNITSn + ug];
        }
        size_t off = (size_t)rowg * UNITSn + ug;
        double cold = cst[off];
        double ig = hsigd(zi), fg = hsigd(zf), og = hsigd(zo);
        double cn = fg * cold + ig * tanh(zc);
        double hn = og * tanh(cn);
        cst[off] = cn;
        hout[off] = hn;
    }
}

// ---------------- Kernel C: logits = h@Wout + bout (fp64), fused argmax ----
#define C_RT 8
#define C_CT 64
#define C_KC 32

__global__ __launch_bounds__(256) void logits_argmax(
    const double* __restrict__ h, const float* __restrict__ Wout,
    const float* __restrict__ bout, u64* __restrict__ slots)
{
    __shared__ double Hs[C_KC][9];     // 2304 B, stride 9 doubles
    __shared__ float  Ws[C_KC][C_CT];  // 8 KB

    const int tid = threadIdx.x;
    const int ty = tid >> 5;           // 0..7 row
    const int tx = tid & 31;           // 2 cols each
    const int rbase = blockIdx.y * C_RT;
    const int cbase = blockIdx.x * C_CT;

    double acc0 = 0.0, acc1 = 0.0;

    const int lh_row = tid >> 5;
    const int lh_kk = tid & 31;
    const int lw_kk = tid >> 4;
    const int lw_j0 = (tid & 15) * 4;

    for (int kb = 0; kb < UNITSn; kb += C_KC) {
        Hs[lh_kk][lh_row] = h[(size_t)(rbase + lh_row) * UNITSn + kb + lh_kk];
        #pragma unroll
        for (int it = 0; it < 2; it++) {
            int kk = lw_kk + it * 16;
            float4 v = *(const float4*)(Wout + (size_t)(kb + kk) * NCn + cbase + lw_j0);
            *(float4*)&Ws[kk][lw_j0] = v;
        }
        __syncthreads();
        #pragma unroll
        for (int kk = 0; kk < C_KC; kk++) {
            double a = Hs[kk][ty];
            float2 w = *(const float2*)&Ws[kk][tx * 2];
            acc0 = fma(a, (double)w.x, acc0);
            acc1 = fma(a, (double)w.y, acc1);
        }
        __syncthreads();
    }

    int col0 = cbase + tx * 2;
    double lg0 = acc0 + (double)bout[col0];
    double lg1 = acc1 + (double)bout[col0 + 1];

    u64 p0 = packlc(lg0, col0);
    u64 p1 = packlc(lg1, col0 + 1);
    u64 best = (p0 > p1) ? p0 : p1;
    #pragma unroll
    for (int off = 16; off >= 1; off >>= 1) {
        u64 o = __shfl_down(best, off, 32);
        if (o > best) best = o;
    }
    if (tx == 0) atomicMax(&slots[rbase + ty], best);
}

// ---------------- final step decode ----------------
__global__ void final_decode(const u64* __restrict__ slots, int* __restrict__ out) {
    int b = threadIdx.x;
    u64 s = slots[b];
    out[(size_t)b * Tn + (Tn - 1)] = 1023 - (int)(s & 1023ull);
}

extern "C" void kernel_launch(void* const* d_in, const int* in_sizes, int n_in,
                              void* d_out, int out_size, void* d_ws, size_t ws_size,
                              hipStream_t stream) {
    const float* x    = (const float*)d_in[0];
    const float* W    = (const float*)d_in[1];
    const float* U    = (const float*)d_in[2];
    const float* bias = (const float*)d_in[3];
    const float* Wout = (const float*)d_in[4];
    const float* bout = (const float*)d_in[5];
    int* out = (int*)d_out;
    char* ws = (char*)d_ws;

    // ws layout: h0 (2MB) | h1 (2MB) | c (2MB) | slots0 (2KB) | slots1 (2KB)
    double* h0 = (double*)(ws);
    double* h1 = (double*)(ws + (2u << 20));
    double* c  = (double*)(ws + (4u << 20));
    u64* slots0 = (u64*)(ws + (6u << 20));
    u64* slots1 = (u64*)(ws + (6u << 20) + 2048);

    // ws is re-poisoned to 0xAA before every call: zero h/c/slots
    hipMemsetAsync(d_ws, 0, (6u << 20) + 4096, stream);

    for (int t = 0; t < Tn; t++) {
        double* hin  = (t & 1) ? h1 : h0;
        double* hout = (t & 1) ? h0 : h1;
        u64* sprev = (t & 1) ? slots0 : slots1;   // written by C(t-1)
        u64* scur  = (t & 1) ? slots1 : slots0;   // zeroed by A(t), written by C(t)
        lstm_step<<<dim3(64, 4), 256, 0, stream>>>(x, W, U, bias, hin, hout, c,
                                                   sprev, scur, out, t);
        logits_argmax<<<dim3(8, 32), 256, 0, stream>>>(hout, Wout, bout, scur);
    }
    // t = T-1 = 255 (odd) -> its slots live in slots1
    final_decode<<<1, Bn, 0, stream>>>(slots1, out);
}

// Round 4
// 38285.455 us; speedup vs baseline: 1.2682x; 1.2682x over previous
//
#include <hip/hip_runtime.h>
#include <math.h>
#include <stdint.h>

#define Bn 256
#define Tn 256
#define Dn 512
#define UNITSn 1024
#define NCn 512
#define G4n 4096
#define KTn 1536   // 512 (x) + 1024 (h)
#define NT 48      // K tiles of 32

typedef unsigned long long u64;

__device__ __forceinline__ double hsigd(double z) {
    return fmin(fmax(0.2 * z + 0.5, 0.0), 1.0);
}

// pack logit+col into u64: fixed-point (logit+2048)*2^40 (<<10) | (1023-col)
// monotone in logit (9.1e-13 resolution), ties -> smallest col (numpy first-max)
__device__ __forceinline__ u64 packlc(double v, int col) {
    double s = (v + 2048.0) * 1099511627776.0;   // 2^40
    u64 q = (u64)s;                              // < 2^53
    return (q << 10) | (u64)(1023 - col);
}

// ---------------- Kernel A: z = x_t@Wx + h@U (+ W[512+idx] + b) -> gates -> c,h ----
// Tile: 64 batch rows x 32 cols (4 gates x 8 units). K = 1536, fp64 vector FMA.
// Grid 512 linear (ut = bid&127 unit-tile, yt = bid>>7 row-tile) -> 2 blocks/CU.
// 256 threads = 4 waves, microtile 2 rows x 4 cols, double-buffered LDS.
__global__ __launch_bounds__(256, 2) void lstm_step(
    const float* __restrict__ x, const float* __restrict__ W,
    const float* __restrict__ U, const float* __restrict__ bias,
    const double* __restrict__ hin, double* __restrict__ hout,
    double* __restrict__ cst,
    const u64* __restrict__ slots_prev, u64* __restrict__ slots_cur,
    int* __restrict__ out, int t)
{
    // Flat LDS (all double, legal aliasing):
    //   As[p] = smem + p*2048   : [32 k][64 rows]
    //   Bs[p] = smem + 4096 + p*1024 : [32 k][32 cols]
    //   zex   = smem + 0        : [64 rows][32 cols]  (reuses As after K loop)
    __shared__ __align__(16) double smem[6144];   // 49152 B

    const int tid = threadIdx.x;
    const int bid = blockIdx.x;
    const int ut = bid & 127;          // unit tile: 8 units
    const int yt = bid >> 7;           // row tile: 64 rows
    const int u0 = ut * 8;
    const int rowbase = yt * 64;

    // zero the slot buffer C(t) will atomicMax into
    if (ut == 0 && tid < 64) slots_cur[rowbase + tid] = 0ull;

    // ---- loader mappings ----
    const int la_row = tid >> 2;            // 0..63
    const int la_k0 = (tid & 3) * 8;        // 0,8,16,24
    const int lb_k  = tid >> 3;             // 0..31
    const int lb_c4 = (tid & 7) * 4;        // 0,4,...,28
    const int lb_gate = lb_c4 >> 3;         // 0..3
    const int lb_uoff = lb_c4 & 7;          // 0 or 4

    const float* xrow = x + (size_t)(rowbase + la_row) * (Tn * Dn) + (size_t)t * Dn;
    const double* hrow = hin + (size_t)(rowbase + la_row) * UNITSn;

    double a_pf[8];
    double b_pf[4];

    auto prefetch = [&](int it) {
        int kg = it * 32;
        int k0 = kg + la_k0;
        if (k0 < Dn) {
            float4 v0 = *(const float4*)(xrow + k0);
            float4 v1 = *(const float4*)(xrow + k0 + 4);
            a_pf[0] = (double)v0.x; a_pf[1] = (double)v0.y;
            a_pf[2] = (double)v0.z; a_pf[3] = (double)v0.w;
            a_pf[4] = (double)v1.x; a_pf[5] = (double)v1.y;
            a_pf[6] = (double)v1.z; a_pf[7] = (double)v1.w;
        } else {
            const double* hp = hrow + (k0 - Dn);
            double2 h0v = *(const double2*)(hp + 0);
            double2 h1v = *(const double2*)(hp + 2);
            double2 h2v = *(const double2*)(hp + 4);
            double2 h3v = *(const double2*)(hp + 6);
            a_pf[0] = h0v.x; a_pf[1] = h0v.y; a_pf[2] = h1v.x; a_pf[3] = h1v.y;
            a_pf[4] = h2v.x; a_pf[5] = h2v.y; a_pf[6] = h3v.x; a_pf[7] = h3v.y;
        }
        int kB = kg + lb_k;
        const float* rowp = (kB < Dn) ? (W + (size_t)kB * G4n)
                                      : (U + (size_t)(kB - Dn) * G4n);
        float4 wv = *(const float4*)(rowp + lb_gate * UNITSn + u0 + lb_uoff);
        b_pf[0] = (double)wv.x; b_pf[1] = (double)wv.y;
        b_pf[2] = (double)wv.z; b_pf[3] = (double)wv.w;
    };
    auto store_tiles = [&](int p) {
        double* As = smem + p * 2048;
        double* Bs = smem + 4096 + p * 1024;
        #pragma unroll
        for (int j = 0; j < 8; j++) As[(la_k0 + j) * 64 + la_row] = a_pf[j];
        double2 w0; w0.x = b_pf[0]; w0.y = b_pf[1];
        double2 w1; w1.x = b_pf[2]; w1.y = b_pf[3];
        *(double2*)&Bs[lb_k * 32 + lb_c4] = w0;
        *(double2*)&Bs[lb_k * 32 + lb_c4 + 2] = w1;
    };

    // ---- compute mapping: wave v rows [16v,16v+16), lane: ri=row-pair, cj=col-quad ----
    const int lane = tid & 63;
    const int wv_ = tid >> 6;
    const int ri = lane >> 3;          // 0..7
    const int cj = lane & 7;           // 0..7
    const int rb = wv_ * 16 + ri * 2;  // even row base 0..62

    double acc[2][4];
    #pragma unroll
    for (int i = 0; i < 2; i++)
        #pragma unroll
        for (int j = 0; j < 4; j++) acc[i][j] = 0.0;

    prefetch(0);
    store_tiles(0);
    __syncthreads();

    int p = 0;
    for (int it = 0; it < NT; it++) {
        if (it + 1 < NT) prefetch(it + 1);
        {
            const double* As = smem + p * 2048;
            const double* Bs = smem + 4096 + p * 1024;
            #pragma unroll
            for (int k = 0; k < 32; k++) {
                double2 a2 = *(const double2*)&As[k * 64 + rb];
                double2 b0 = *(const double2*)&Bs[k * 32 + cj * 4];
                double2 b1 = *(const double2*)&Bs[k * 32 + cj * 4 + 2];
                acc[0][0] = fma(a2.x, b0.x, acc[0][0]);
                acc[0][1] = fma(a2.x, b0.y, acc[0][1]);
                acc[0][2] = fma(a2.x, b1.x, acc[0][2]);
                acc[0][3] = fma(a2.x, b1.y, acc[0][3]);
                acc[1][0] = fma(a2.y, b0.x, acc[1][0]);
                acc[1][1] = fma(a2.y, b0.y, acc[1][1]);
                acc[1][2] = fma(a2.y, b1.x, acc[1][2]);
                acc[1][3] = fma(a2.y, b1.y, acc[1][3]);
            }
        }
        if (it + 1 < NT) store_tiles(p ^ 1);
        __syncthreads();
        p ^= 1;
    }

    // ---- gate exchange: zex[64][32] aliases As region (safe after final barrier) ----
    double* zex = smem;
    #pragma unroll
    for (int i = 0; i < 2; i++) {
        double2 z0; z0.x = acc[i][0]; z0.y = acc[i][1];
        double2 z1; z1.x = acc[i][2]; z1.y = acc[i][3];
        *(double2*)&zex[(rb + i) * 32 + cj * 4] = z0;
        *(double2*)&zex[(rb + i) * 32 + cj * 4 + 2] = z1;
    }
    __syncthreads();

    // ---- epilogue: 2 cells/thread (row rr & rr+32, unit eu) ----
    const int eu = tid & 7;
    const int rr = tid >> 3;           // 0..31
    const int ug = u0 + eu;
    const double bi0 = (double)bias[ug];
    const double bf0 = (double)bias[UNITSn + ug];
    const double bc0 = (double)bias[2 * UNITSn + ug];
    const double bo0 = (double)bias[3 * UNITSn + ug];

    #pragma unroll
    for (int s = 0; s < 2; s++) {
        int r = rr + 32 * s;
        int row = rowbase + r;
        double zi = zex[r * 32 + eu]      + bi0;
        double zf = zex[r * 32 + 8 + eu]  + bf0;
        double zc = zex[r * 32 + 16 + eu] + bc0;
        double zo = zex[r * 32 + 24 + eu] + bo0;
        if (t > 0) {
            u64 sp = slots_prev[row];
            int idx = 1023 - (int)(sp & 1023ull);
            const float* wrow = W + (size_t)(Dn + idx) * G4n + ug;
            zi += (double)wrow[0];
            zf += (double)wrow[UNITSn];
            zc += (double)wrow[2 * UNITSn];
            zo += (double)wrow[3 * UNITSn];
            if (ut == 0 && eu == 0) out[(size_t)row * Tn + (t - 1)] = idx;
        }
        size_t off = (size_t)row * UNITSn + ug;
        double cold = cst[off];
        double ig = hsigd(zi), fg = hsigd(zf), og = hsigd(zo);
        double cn = fg * cold + ig * tanh(zc);
        double hn = og * tanh(cn);
        cst[off] = cn;
        hout[off] = hn;
    }
}

// ---------------- Kernel C: logits = h@Wout + bout (fp64), fused argmax ----
// (verbatim from the passing round-2 kernel)
#define C_RT 8
#define C_CT 64
#define C_KC 32

__global__ __launch_bounds__(256) void logits_argmax(
    const double* __restrict__ h, const float* __restrict__ Wout,
    const float* __restrict__ bout, u64* __restrict__ slots)
{
    __shared__ double Hs[C_KC][9];
    __shared__ float  Ws[C_KC][C_CT];

    const int tid = threadIdx.x;
    const int ty = tid >> 5;
    const int tx = tid & 31;
    const int rbase = blockIdx.y * C_RT;
    const int cbase = blockIdx.x * C_CT;

    double acc0 = 0.0, acc1 = 0.0;

    const int lh_row = tid >> 5;
    const int lh_kk = tid & 31;
    const int lw_kk = tid >> 4;
    const int lw_j0 = (tid & 15) * 4;

    for (int kb = 0; kb < UNITSn; kb += C_KC) {
        Hs[lh_kk][lh_row] = h[(size_t)(rbase + lh_row) * UNITSn + kb + lh_kk];
        #pragma unroll
        for (int it = 0; it < 2; it++) {
            int kk = lw_kk + it * 16;
            float4 v = *(const float4*)(Wout + (size_t)(kb + kk) * NCn + cbase + lw_j0);
            *(float4*)&Ws[kk][lw_j0] = v;
        }
        __syncthreads();
        #pragma unroll
        for (int kk = 0; kk < C_KC; kk++) {
            double a = Hs[kk][ty];
            float2 wv = *(const float2*)&Ws[kk][tx * 2];
            acc0 = fma(a, (double)wv.x, acc0);
            acc1 = fma(a, (double)wv.y, acc1);
        }
        __syncthreads();
    }

    int col0 = cbase + tx * 2;
    double lg0 = acc0 + (double)bout[col0];
    double lg1 = acc1 + (double)bout[col0 + 1];

    u64 p0 = packlc(lg0, col0);
    u64 p1 = packlc(lg1, col0 + 1);
    u64 best = (p0 > p1) ? p0 : p1;
    #pragma unroll
    for (int off = 16; off >= 1; off >>= 1) {
        u64 o = __shfl_down(best, off, 32);
        if (o > best) best = o;
    }
    if (tx == 0) atomicMax(&slots[rbase + ty], best);
}

// ---------------- final step decode ----------------
__global__ void final_decode(const u64* __restrict__ slots, int* __restrict__ out) {
    int b = threadIdx.x;
    u64 s = slots[b];
    out[(size_t)b * Tn + (Tn - 1)] = 1023 - (int)(s & 1023ull);
}

extern "C" void kernel_launch(void* const* d_in, const int* in_sizes, int n_in,
                              void* d_out, int out_size, void* d_ws, size_t ws_size,
                              hipStream_t stream) {
    const float* x    = (const float*)d_in[0];
    const float* W    = (const float*)d_in[1];
    const float* U    = (const float*)d_in[2];
    const float* bias = (const float*)d_in[3];
    const float* Wout = (const float*)d_in[4];
    const float* bout = (const float*)d_in[5];
    int* out = (int*)d_out;
    char* ws = (char*)d_ws;

    // ws layout: h0 (2MB) | h1 (2MB) | c (2MB) | slots0 (2KB) | slots1 (2KB)
    double* h0 = (double*)(ws);
    double* h1 = (double*)(ws + (2u << 20));
    double* c  = (double*)(ws + (4u << 20));
    u64* slots0 = (u64*)(ws + (6u << 20));
    u64* slots1 = (u64*)(ws + (6u << 20) + 2048);

    hipMemsetAsync(d_ws, 0, (6u << 20) + 4096, stream);

    for (int t = 0; t < Tn; t++) {
        double* hin  = (t & 1) ? h1 : h0;
        double* hout = (t & 1) ? h0 : h1;
        u64* sprev = (t & 1) ? slots0 : slots1;   // written by C(t-1)
        u64* scur  = (t & 1) ? slots1 : slots0;   // zeroed by A(t), written by C(t)
        lstm_step<<<dim3(512), 256, 0, stream>>>(x, W, U, bias, hin, hout, c,
                                                 sprev, scur, out, t);
        logits_argmax<<<dim3(8, 32), 256, 0, stream>>>(hout, Wout, bout, scur);
    }
    // t = T-1 = 255 (odd) -> its slots live in slots1
    final_decode<<<1, Bn, 0, stream>>>(slots1, out);
}